// Round 2
// baseline (182.772 us; speedup 1.0000x reference)
//
#include <hip/hip_runtime.h>

// Problem constants (from reference):
//   depth: [B, D, H, W] fp32,  grid: [B, NN*H, W, 2] fp32 in [-1,1]
//   out  : [B, D+NN, H, W] fp32, sorted ascending along channel axis
constexpr int B  = 4;
constexpr int D  = 8;
constexpr int H  = 512;
constexpr int W  = 640;
constexpr int NN = 9;
constexpr int HW = H * W;
constexpr int NC = D + NN;  // 17

__global__ __launch_bounds__(256) void prop_sort_kernel(
    const float* __restrict__ depth,
    const float* __restrict__ grid,
    float* __restrict__ out) {
  int idx = blockIdx.x * blockDim.x + threadIdx.x;
  if (idx >= B * HW) return;

  int b  = idx / HW;
  int hw = idx - b * HW;
  int h  = hw / W;
  int w  = hw - h * W;

  // ---- phase 1: issue ALL independent loads up front (max MLP) ----

  // 9 grid float2 loads (coalesced, stride H*W)
  const float2* gp = reinterpret_cast<const float2*>(grid)
                     + ((size_t)b * NN * H + h) * W + w;
  float2 g[NN];
#pragma unroll
  for (int n = 0; n < NN; ++n) {
    g[n] = gp[(size_t)n * HW];
  }

  // 8 depth-channel loads (coalesced, stride H*W)
  const float* dptr = depth + (size_t)b * D * HW + hw;
  float v[NC];
#pragma unroll
  for (int d = 0; d < D; ++d) {
    v[d] = dptr[(size_t)d * HW];
  }

  // ---- phase 2: compute all 36 gather offsets (32-bit, saddr-form) ----
  float wx[NN], wy[NN];
  unsigned off00[NN], off01[NN], off10[NN], off11[NN];
#pragma unroll
  for (int n = 0; n < NN; ++n) {
    float ix = ((g[n].x + 1.0f) * (float)W - 1.0f) * 0.5f;
    float iy = ((g[n].y + 1.0f) * (float)H - 1.0f) * 0.5f;
    ix = fminf(fmaxf(ix, 0.0f), (float)(W - 1));
    iy = fminf(fmaxf(iy, 0.0f), (float)(H - 1));

    float x0f = floorf(ix);
    float y0f = floorf(iy);
    wx[n] = ix - x0f;
    wy[n] = iy - y0f;

    int x0 = (int)x0f;
    int y0 = (int)y0f;
    int x1 = min(x0 + 1, W - 1);
    int y1 = min(y0 + 1, H - 1);

    off00[n] = (unsigned)(y0 * W + x0);
    off01[n] = (unsigned)(y0 * W + x1);
    off10[n] = (unsigned)(y1 * W + x0);
    off11[n] = (unsigned)(y1 * W + x1);
  }

  // ---- phase 3: issue ALL 36 gathers before consuming any ----
  const float* center = depth + (size_t)b * D * HW + (size_t)(D / 2) * HW;
  float v00[NN], v01[NN], v10[NN], v11[NN];
#pragma unroll
  for (int n = 0; n < NN; ++n) v00[n] = center[off00[n]];
#pragma unroll
  for (int n = 0; n < NN; ++n) v01[n] = center[off01[n]];
#pragma unroll
  for (int n = 0; n < NN; ++n) v10[n] = center[off10[n]];
#pragma unroll
  for (int n = 0; n < NN; ++n) v11[n] = center[off11[n]];

  // ---- phase 4: bilinear combine ----
#pragma unroll
  for (int n = 0; n < NN; ++n) {
    float vtop = v00[n] * (1.0f - wx[n]) + v01[n] * wx[n];
    float vbot = v10[n] * (1.0f - wx[n]) + v11[n] * wx[n];
    v[D + n] = vtop * (1.0f - wy[n]) + vbot * wy[n];
  }

  // ---- phase 5: sort 17 values (odd-even transposition, branch-free) ----
#pragma unroll
  for (int pass = 0; pass < NC; ++pass) {
#pragma unroll
    for (int i = (pass & 1); i + 1 < NC; i += 2) {
      float lo = fminf(v[i], v[i + 1]);
      float hi = fmaxf(v[i], v[i + 1]);
      v[i] = lo;
      v[i + 1] = hi;
    }
  }

  // ---- phase 6: write 17 output planes (coalesced) ----
  float* optr = out + (size_t)b * NC * HW + hw;
#pragma unroll
  for (int c = 0; c < NC; ++c) {
    optr[(size_t)c * HW] = v[c];
  }
}

extern "C" void kernel_launch(void* const* d_in, const int* in_sizes, int n_in,
                              void* d_out, int out_size, void* d_ws, size_t ws_size,
                              hipStream_t stream) {
  const float* depth = (const float*)d_in[0];
  const float* grid  = (const float*)d_in[1];
  float* out = (float*)d_out;

  int total = B * HW;           // 1,310,720 threads (one per output pixel)
  int block = 256;
  int nblocks = (total + block - 1) / block;  // 5120
  prop_sort_kernel<<<nblocks, block, 0, stream>>>(depth, grid, out);
}

// Round 3
// 113.179 us; speedup vs baseline: 1.6149x; 1.6149x over previous
//
#include <hip/hip_runtime.h>

// Problem constants (from reference):
//   depth: [B, D, H, W] fp32,  grid: [B, NN*H, W, 2] fp32 in [-1,1]
//   out  : [B, D+NN, H, W] fp32, sorted ascending along channel axis
constexpr int B  = 4;
constexpr int D  = 8;
constexpr int H  = 512;
constexpr int W  = 640;
constexpr int NN = 9;
constexpr int HW = H * W;
constexpr int NC = D + NN;  // 17

// 8-byte pair with only 4-byte alignment guarantee: lets the compiler emit
// global_load_dwordx2 (gfx950 unaligned-access mode) for [x0, x0+1] pairs.
struct __attribute__((packed, aligned(4))) fpair { float a, b; };

__global__ __launch_bounds__(256) void prop_sort_kernel(
    const float* __restrict__ depth,
    const float* __restrict__ grid,
    float* __restrict__ out) {
  int idx = blockIdx.x * blockDim.x + threadIdx.x;
  if (idx >= B * HW) return;

  int b  = idx / HW;
  int hw = idx - b * HW;
  int h  = hw / W;
  int w  = hw - h * W;

  float v[NC];

  // ---- load the 8 depth channels (coalesced plane-strided reads) ----
  const float* dptr = depth + (size_t)b * D * HW + hw;
#pragma unroll
  for (int d = 0; d < D; ++d) {
    v[d] = dptr[(size_t)d * HW];
  }

  // ---- bilinear grid_sample of the center plane, border padding ----
  const float* center = depth + (size_t)b * D * HW + (size_t)(D / 2) * HW;
  // grid viewed as float2 [B, NN*H, W]
  const float2* gp = reinterpret_cast<const float2*>(grid)
                     + ((size_t)b * NN * H + h) * W + w;

#pragma unroll
  for (int n = 0; n < NN; ++n) {
    float2 g = gp[(size_t)n * HW];
    float gx = g.x, gy = g.y;

    float ix = ((gx + 1.0f) * (float)W - 1.0f) * 0.5f;
    float iy = ((gy + 1.0f) * (float)H - 1.0f) * 0.5f;
    ix = fminf(fmaxf(ix, 0.0f), (float)(W - 1));
    iy = fminf(fmaxf(iy, 0.0f), (float)(H - 1));

    float x0f = floorf(ix);
    float y0f = floorf(iy);
    float wx = ix - x0f;
    float wy = iy - y0f;

    int x0 = (int)x0f;
    int y0 = (int)y0f;
    int y1 = min(y0 + 1, H - 1);

    // One 8B pair-load per row: covers (x0, x0+1). When wx == 0 the second
    // element has weight 0, and wx > 0 implies x0 <= W-2, so pair.b is
    // either exact or harmlessly weighted by zero (values are finite).
    fpair p0 = *reinterpret_cast<const fpair*>(center + y0 * W + x0);
    fpair p1 = *reinterpret_cast<const fpair*>(center + y1 * W + x0);

    float vtop = p0.a * (1.0f - wx) + p0.b * wx;
    float vbot = p1.a * (1.0f - wx) + p1.b * wx;
    v[D + n] = vtop * (1.0f - wy) + vbot * wy;
  }

  // ---- sort 17 values: branch-free odd-even transposition network ----
#pragma unroll
  for (int pass = 0; pass < NC; ++pass) {
#pragma unroll
    for (int i = (pass & 1); i + 1 < NC; i += 2) {
      float lo = fminf(v[i], v[i + 1]);
      float hi = fmaxf(v[i], v[i + 1]);
      v[i] = lo;
      v[i + 1] = hi;
    }
  }

  // ---- write 17 output planes (coalesced) ----
  float* optr = out + (size_t)b * NC * HW + hw;
#pragma unroll
  for (int c = 0; c < NC; ++c) {
    optr[(size_t)c * HW] = v[c];
  }
}

extern "C" void kernel_launch(void* const* d_in, const int* in_sizes, int n_in,
                              void* d_out, int out_size, void* d_ws, size_t ws_size,
                              hipStream_t stream) {
  const float* depth = (const float*)d_in[0];
  const float* grid  = (const float*)d_in[1];
  float* out = (float*)d_out;

  int total = B * HW;           // 1,310,720 threads (one per output pixel)
  int block = 256;
  int nblocks = (total + block - 1) / block;  // 5120
  prop_sort_kernel<<<nblocks, block, 0, stream>>>(depth, grid, out);
}